// Round 6
// baseline (313.733 us; speedup 1.0000x reference)
//
#include <hip/hip_runtime.h>
#include <hip/hip_bf16.h>

typedef short bf16x8 __attribute__((ext_vector_type(8)));
typedef __bf16 bfv8  __attribute__((ext_vector_type(8)));
typedef float f32x4  __attribute__((ext_vector_type(4)));

#define S_LEN 4096
#define DDIM  64
#define KVB   32
#define QBLK  128               // q rows per block (4 waves x 32)
#define NHEAD 16
#define THR   7.0f              // defer-max threshold (log2 domain)

#define MFMA(a, b, c) __builtin_amdgcn_mfma_f32_16x16x32_bf16((a), (b), (c), 0, 0, 0)

// base-2 exp via v_exp_f32 (avoid __exp2f: glibc macro collision)
static __device__ __forceinline__ float exp2v(float x) {
    return __builtin_amdgcn_exp2f(x);
}

// exact truncation pack: both floats carry exact bf16 values -> take top16
static __device__ __forceinline__ unsigned pk2t(float lo, float hi) {
    return __builtin_amdgcn_perm(__builtin_bit_cast(unsigned, hi),
                                 __builtin_bit_cast(unsigned, lo), 0x07060302u);
}

// 8x fp32 -> bf16 RNE via native __bf16 casts (compiler fuses to v_cvt_pk_bf16_f32)
static __device__ __forceinline__ int4 cvt8(float4 a, float4 b) {
    bfv8 r;
    r[0] = (__bf16)a.x; r[1] = (__bf16)a.y; r[2] = (__bf16)a.z; r[3] = (__bf16)a.w;
    r[4] = (__bf16)b.x; r[5] = (__bf16)b.y; r[6] = (__bf16)b.z; r[7] = (__bf16)b.w;
    return __builtin_bit_cast(int4, r);
}

// fragment read from row-major [32][64] bf16 LDS tile, XOR-swizzled
static __device__ __forceinline__ bf16x8 ldfrag(const unsigned char* base, int row, int doff) {
    int addr = (row * 128 + doff * 2) ^ ((row & 7) << 4);
    return *reinterpret_cast<const bf16x8*>(base + addr);
}

// stage one K/V 32x64 tile pair (fp32 regs -> bf16 -> swizzled LDS b128 writes)
static __device__ __forceinline__ void stage(unsigned char* base, int swaddr,
                                             float4 a, float4 b, float4 c, float4 d) {
    *reinterpret_cast<int4*>(base + swaddr)        = cvt8(a, b);
    *reinterpret_cast<int4*>(base + 4096 + swaddr) = cvt8(c, d);
}

// online softmax + PV accumulate for one 16-row q-set (base-2 domain).
// Common path: NO cross-lane ops (in-lane defer-max; l accumulated by ones-MFMA).
static __device__ __forceinline__ void sm_pv(f32x4 s0, f32x4 s1, float& m,
                                             f32x4 acc[4], f32x4& lacc,
                                             const bf16x8 vf[4], bf16x8 ones) {
    // in-lane max of this lane's 8 scores (max3-fusable chain)
    float mx = fmaxf(fmaxf(fmaxf(s0[0], s0[1]), s0[2]),
                     fmaxf(fmaxf(s0[3], s1[0]),
                           fmaxf(s1[1], fmaxf(s1[2], s1[3]))));
    if (!__all(mx <= m + THR)) {        // rare: true max grew past headroom
        float pm = fmaxf(mx, __shfl_xor(mx, 16));
        pm = fmaxf(pm, __shfl_xor(pm, 32));
        float mn = fmaxf(m, pm);
        float al = exp2v(m - mn);
        #pragma unroll
        for (int dk = 0; dk < 4; ++dk)
            #pragma unroll
            for (int j = 0; j < 4; ++j) acc[dk][j] *= al;
        #pragma unroll
        for (int j = 0; j < 4; ++j) lacc[j] *= al;
        m = mn;
    }
    float p[8];
    #pragma unroll
    for (int j = 0; j < 4; ++j) p[j]     = exp2v(s0[j] - m);
    #pragma unroll
    for (int j = 0; j < 4; ++j) p[4 + j] = exp2v(s1[j] - m);
    bfv8 r;
    #pragma unroll
    for (int j = 0; j < 8; ++j) r[j] = (__bf16)p[j];
    bf16x8 pb = __builtin_bit_cast(bf16x8, r);
    lacc = MFMA(ones, pb, lacc);         // row-sum of P on the matrix pipe
    #pragma unroll
    for (int dk = 0; dk < 4; ++dk) acc[dk] = MFMA(vf[dk], pb, acc[dk]);
}

template <int KSPLIT>
__global__ __launch_bounds__(256, 4) void attn_fwd(
    const float* __restrict__ Qg, const float* __restrict__ Kg,
    const float* __restrict__ Vg, float* __restrict__ Og,
    float* __restrict__ wsO, float* __restrict__ wsML)
{
    const int h    = blockIdx.y;
    const int qb   = blockIdx.x;
    const int ks   = (KSPLIT > 1) ? blockIdx.z : 0;
    const int NT   = (S_LEN / KVB) / KSPLIT;
    const int tid  = threadIdx.x;
    const int lane = tid & 63;
    const int wv   = tid >> 6;      // wave 0..3, each owns 32 q rows
    const int g    = lane >> 4;     // lane group 0..3
    const int r16  = lane & 15;

    __shared__ __align__(16) unsigned char lds[16384];   // 2 bufs x (K 4K + V 4K)

    // ---- Q fragments: 2 sets of 16 rows, pre-scaled by log2(e)/sqrt(D) ----
    const float QSC = 0.125f * 1.44269504088896f;
    const int qrow0 = qb * QBLK + wv * 32 + r16;
    bf16x8 qf0[2], qf1[2];
    {
        const float* qp0 = Qg + ((size_t)h * S_LEN + qrow0) * DDIM;
        const float* qp1 = qp0 + 16 * DDIM;
        #pragma unroll
        for (int c = 0; c < 2; ++c) {
            float4 x = *reinterpret_cast<const float4*>(qp0 + 32 * c + 8 * g);
            float4 y = *reinterpret_cast<const float4*>(qp0 + 32 * c + 8 * g + 4);
            float4 xs = {x.x * QSC, x.y * QSC, x.z * QSC, x.w * QSC};
            float4 ys = {y.x * QSC, y.y * QSC, y.z * QSC, y.w * QSC};
            qf0[c] = __builtin_bit_cast(bf16x8, cvt8(xs, ys));
            x = *reinterpret_cast<const float4*>(qp1 + 32 * c + 8 * g);
            y = *reinterpret_cast<const float4*>(qp1 + 32 * c + 8 * g + 4);
            xs = {x.x * QSC, x.y * QSC, x.z * QSC, x.w * QSC};
            ys = {y.x * QSC, y.y * QSC, y.z * QSC, y.w * QSC};
            qf1[c] = __builtin_bit_cast(bf16x8, cvt8(xs, ys));
        }
    }

    // ---- identity fragments for the V-transpose MFMA (k-map: 8g+e) ----
    bf16x8 idf[2];
    #pragma unroll
    for (int c2 = 0; c2 < 2; ++c2) {
        #pragma unroll
        for (int e = 0; e < 8; ++e) {
            bool on = ((g >> 1) == c2) && ((r16 >> 3) == (g & 1)) && (e == (r16 & 7));
            idf[c2][e] = on ? (short)0x3F80 : (short)0;
        }
    }
    bf16x8 ones;
    #pragma unroll
    for (int e = 0; e < 8; ++e) ones[e] = (short)0x3F80;

    // ---- staging assignment ----
    const int srow   = tid >> 3;
    const int sd     = (tid & 7) * 8;
    const int swaddr = (srow * 128 + sd * 2) ^ ((srow & 7) << 4);
    const size_t kvoff = (size_t)h * S_LEN * DDIM
                       + (size_t)ks * (S_LEN / KSPLIT) * DDIM
                       + (size_t)srow * DDIM + sd;
    const float* kp = Kg + kvoff;
    const float* vp = Vg + kvoff;

    // prologue: tile 0 -> buf0; tile 1 -> regs
    float4 ka = *reinterpret_cast<const float4*>(kp);
    float4 kb = *reinterpret_cast<const float4*>(kp + 4);
    float4 va = *reinterpret_cast<const float4*>(vp);
    float4 vb = *reinterpret_cast<const float4*>(vp + 4);
    stage(lds, swaddr, ka, kb, va, vb);
    kp += KVB * DDIM; vp += KVB * DDIM;
    ka = *reinterpret_cast<const float4*>(kp);
    kb = *reinterpret_cast<const float4*>(kp + 4);
    va = *reinterpret_cast<const float4*>(vp);
    vb = *reinterpret_cast<const float4*>(vp + 4);
    __syncthreads();

    const f32x4 z0 = {0.f, 0.f, 0.f, 0.f};
    f32x4 accA[4] = {z0, z0, z0, z0};    // set0: d = 16dk+4g+j, q = r16
    f32x4 accB[4] = {z0, z0, z0, z0};    // set1: q = 16 + r16
    f32x4 laccA = z0, laccB = z0;        // running softmax denominators
    float m0 = -INFINITY, m1 = -INFINITY;

    int c = 0;
    for (int kt = 0; kt < NT; ++kt) {
        const unsigned char* Klds = lds + c * 8192;
        const unsigned char* Vlds = lds + c * 8192 + 4096;

        // write next tile into other buffer; issue loads for tile kt+2
        if (kt + 1 < NT) {
            stage(lds + (c ^ 1) * 8192, swaddr, ka, kb, va, vb);
            if (kt + 2 < NT) {
                kp += KVB * DDIM; vp += KVB * DDIM;
                ka = *reinterpret_cast<const float4*>(kp);
                kb = *reinterpret_cast<const float4*>(kp + 4);
                va = *reinterpret_cast<const float4*>(vp);
                vb = *reinterpret_cast<const float4*>(vp + 4);
            }
        }

        // ---- QK^T (swapped): S^T tiles; keys 4g+j (+16), q = r16 ----
        f32x4 sA0 = z0, sA1 = z0, sB0 = z0, sB1 = z0;
        #pragma unroll
        for (int cc = 0; cc < 2; ++cc) {
            bf16x8 k0 = ldfrag(Klds, r16,      32 * cc + 8 * g);
            bf16x8 k1 = ldfrag(Klds, 16 + r16, 32 * cc + 8 * g);
            sA0 = MFMA(k0, qf0[cc], sA0);
            sA1 = MFMA(k1, qf0[cc], sA1);
            sB0 = MFMA(k0, qf1[cc], sB0);
            sB1 = MFMA(k1, qf1[cc], sB1);
        }

        // ---- V^T via identity-MFMA (per-dc to limit live registers) ----
        bf16x8 vf[4];
        #pragma unroll
        for (int dc = 0; dc < 2; ++dc) {
            bf16x8 av0 = ldfrag(Vlds, r16,      32 * dc + 8 * g);
            bf16x8 av1 = ldfrag(Vlds, 16 + r16, 32 * dc + 8 * g);
            #pragma unroll
            for (int ci = 0; ci < 2; ++ci) {
                f32x4 t0 = MFMA(av0, idf[ci], z0);
                f32x4 t1 = MFMA(av1, idf[ci], z0);
                int4 w;
                w.x = (int)pk2t(t0[0], t0[1]); w.y = (int)pk2t(t0[2], t0[3]);
                w.z = (int)pk2t(t1[0], t1[1]); w.w = (int)pk2t(t1[2], t1[3]);
                vf[2 * dc + ci] = __builtin_bit_cast(bf16x8, w);
            }
        }

        sm_pv(sA0, sA1, m0, accA, laccA, vf, ones);
        sm_pv(sB0, sB1, m1, accB, laccB, vf, ones);

        __syncthreads();
        c ^= 1;
    }

    // ---- epilogue (every lane holds the full denominator in lacc[0]) ----
    if (KSPLIT == 1) {
        float inv0 = 1.0f / laccA[0];
        float* op = Og + ((size_t)h * S_LEN + qrow0) * DDIM;
        #pragma unroll
        for (int dk = 0; dk < 4; ++dk) {
            float4 o = {accA[dk][0] * inv0, accA[dk][1] * inv0,
                        accA[dk][2] * inv0, accA[dk][3] * inv0};
            *reinterpret_cast<float4*>(op + 16 * dk + 4 * g) = o;
        }
        float inv1 = 1.0f / laccB[0];
        op += 16 * DDIM;
        #pragma unroll
        for (int dk = 0; dk < 4; ++dk) {
            float4 o = {accB[dk][0] * inv1, accB[dk][1] * inv1,
                        accB[dk][2] * inv1, accB[dk][3] * inv1};
            *reinterpret_cast<float4*>(op + 16 * dk + 4 * g) = o;
        }
    } else {
        // unnormalized partials + (m, l) per row
        const size_t R0 = (size_t)h * S_LEN + qrow0;
        float* o0 = wsO + ((size_t)ks * (NHEAD * S_LEN) + R0) * DDIM;
        #pragma unroll
        for (int dk = 0; dk < 4; ++dk) {
            float4 o = {accA[dk][0], accA[dk][1], accA[dk][2], accA[dk][3]};
            *reinterpret_cast<float4*>(o0 + 16 * dk + 4 * g) = o;
        }
        o0 += 16 * DDIM;
        #pragma unroll
        for (int dk = 0; dk < 4; ++dk) {
            float4 o = {accB[dk][0], accB[dk][1], accB[dk][2], accB[dk][3]};
            *reinterpret_cast<float4*>(o0 + 16 * dk + 4 * g) = o;
        }
        if (g == 0) {
            float2 v0 = {m0, laccA[0]};
            float2 v1 = {m1, laccB[0]};
            *reinterpret_cast<float2*>(wsML + ((size_t)ks * (NHEAD * S_LEN) + R0) * 2)      = v0;
            *reinterpret_cast<float2*>(wsML + ((size_t)ks * (NHEAD * S_LEN) + R0 + 16) * 2) = v1;
        }
    }
}

__global__ __launch_bounds__(256) void combine2(
    const float* __restrict__ wsO, const float* __restrict__ wsML,
    float* __restrict__ Og)
{
    const int NR = NHEAD * S_LEN;
    int t  = blockIdx.x * 256 + threadIdx.x;     // one float4 of O per thread
    int R  = t >> 4;
    int d4 = (t & 15) * 4;
    float2 ml0 = *reinterpret_cast<const float2*>(wsML + (size_t)R * 2);
    float2 ml1 = *reinterpret_cast<const float2*>(wsML + ((size_t)NR + R) * 2);
    float m  = fmaxf(ml0.x, ml1.x);
    float a0 = exp2v(ml0.x - m);
    float a1 = exp2v(ml1.x - m);
    float inv = 1.0f / (a0 * ml0.y + a1 * ml1.y);
    a0 *= inv; a1 *= inv;
    float4 o0 = *reinterpret_cast<const float4*>(wsO + (size_t)R * DDIM + d4);
    float4 o1 = *reinterpret_cast<const float4*>(wsO + ((size_t)NR + R) * DDIM + d4);
    float4 o = {a0 * o0.x + a1 * o1.x, a0 * o0.y + a1 * o1.y,
                a0 * o0.z + a1 * o1.z, a0 * o0.w + a1 * o1.w};
    *reinterpret_cast<float4*>(Og + (size_t)R * DDIM + d4) = o;
}

extern "C" void kernel_launch(void* const* d_in, const int* in_sizes, int n_in,
                              void* d_out, int out_size, void* d_ws, size_t ws_size,
                              hipStream_t stream) {
    const float* Q = (const float*)d_in[0];
    const float* K = (const float*)d_in[1];
    const float* V = (const float*)d_in[2];
    float* O = (float*)d_out;

    const size_t nO  = (size_t)2 * NHEAD * S_LEN * DDIM;   // partial O floats
    const size_t nML = (size_t)2 * NHEAD * S_LEN * 2;      // (m,l) floats
    const size_t need = (nO + nML) * sizeof(float);

    if (ws_size >= need) {
        float* wsO  = (float*)d_ws;
        float* wsML = wsO + nO;
        dim3 grid(S_LEN / QBLK, NHEAD, 2);
        attn_fwd<2><<<grid, dim3(256, 1, 1), 0, stream>>>(Q, K, V, O, wsO, wsML);
        int nthr = NHEAD * S_LEN * (DDIM / 4);
        combine2<<<dim3(nthr / 256), dim3(256, 1, 1), 0, stream>>>(wsO, wsML, O);
    } else {
        dim3 grid(S_LEN / QBLK, NHEAD, 1);
        attn_fwd<1><<<grid, dim3(256, 1, 1), 0, stream>>>(Q, K, V, O, nullptr, nullptr);
    }
}

// Round 7
// 124.283 us; speedup vs baseline: 2.5243x; 2.5243x over previous
//
#include <hip/hip_runtime.h>
#include <hip/hip_bf16.h>

typedef short bf16x8 __attribute__((ext_vector_type(8)));
typedef __bf16 bfv8  __attribute__((ext_vector_type(8)));
typedef float f32x4  __attribute__((ext_vector_type(4)));

#define S_LEN 4096
#define DDIM  64
#define KVB   32
#define QBLK  128               // q rows per block (4 waves x 32)
#define NHEAD 16
#define THR   7.0f              // defer-max threshold (log2 domain)

#define MFMA(a, b, c) __builtin_amdgcn_mfma_f32_16x16x32_bf16((a), (b), (c), 0, 0, 0)

// base-2 exp via v_exp_f32 (avoid __exp2f: glibc macro collision)
static __device__ __forceinline__ float exp2v(float x) {
    return __builtin_amdgcn_exp2f(x);
}

// exact truncation pack: both floats carry exact bf16 values -> take top16
static __device__ __forceinline__ unsigned pk2t(float lo, float hi) {
    return __builtin_amdgcn_perm(__builtin_bit_cast(unsigned, hi),
                                 __builtin_bit_cast(unsigned, lo), 0x07060302u);
}

// 8x fp32 -> bf16 RNE via native __bf16 casts (compiler fuses to v_cvt_pk_bf16_f32)
static __device__ __forceinline__ int4 cvt8(float4 a, float4 b) {
    bfv8 r;
    r[0] = (__bf16)a.x; r[1] = (__bf16)a.y; r[2] = (__bf16)a.z; r[3] = (__bf16)a.w;
    r[4] = (__bf16)b.x; r[5] = (__bf16)b.y; r[6] = (__bf16)b.z; r[7] = (__bf16)b.w;
    return __builtin_bit_cast(int4, r);
}

// fragment read from row-major [32][64] bf16 LDS tile, XOR-swizzled
static __device__ __forceinline__ bf16x8 ldfrag(const unsigned char* base, int row, int doff) {
    int addr = (row * 128 + doff * 2) ^ ((row & 7) << 4);
    return *reinterpret_cast<const bf16x8*>(base + addr);
}

// stage one K/V 32x64 tile pair (fp32 regs -> bf16 -> swizzled LDS b128 writes)
static __device__ __forceinline__ void stage(unsigned char* base, int swaddr,
                                             float4 a, float4 b, float4 c, float4 d) {
    *reinterpret_cast<int4*>(base + swaddr)        = cvt8(a, b);
    *reinterpret_cast<int4*>(base + 4096 + swaddr) = cvt8(c, d);
}

// online softmax + PV accumulate for one 16-row q-set (base-2 domain).
// Common path: NO cross-lane ops (in-lane defer-max; l accumulated by ones-MFMA).
static __device__ __forceinline__ void sm_pv(f32x4 s0, f32x4 s1, float& m,
                                             f32x4 acc[4], f32x4& lacc,
                                             const bf16x8 vf[4], bf16x8 ones) {
    // in-lane max of this lane's 8 scores (max3-fusable chain)
    float mx = fmaxf(fmaxf(fmaxf(s0[0], s0[1]), s0[2]),
                     fmaxf(fmaxf(s0[3], s1[0]),
                           fmaxf(s1[1], fmaxf(s1[2], s1[3]))));
    if (!__all(mx <= m + THR)) {        // rare: true max grew past headroom
        float pm = fmaxf(mx, __shfl_xor(mx, 16));
        pm = fmaxf(pm, __shfl_xor(pm, 32));
        float mn = fmaxf(m, pm);
        float al = exp2v(m - mn);
        #pragma unroll
        for (int dk = 0; dk < 4; ++dk)
            #pragma unroll
            for (int j = 0; j < 4; ++j) acc[dk][j] *= al;
        #pragma unroll
        for (int j = 0; j < 4; ++j) lacc[j] *= al;
        m = mn;
    }
    float p[8];
    #pragma unroll
    for (int j = 0; j < 4; ++j) p[j]     = exp2v(s0[j] - m);
    #pragma unroll
    for (int j = 0; j < 4; ++j) p[4 + j] = exp2v(s1[j] - m);
    bfv8 r;
    #pragma unroll
    for (int j = 0; j < 8; ++j) r[j] = (__bf16)p[j];
    bf16x8 pb = __builtin_bit_cast(bf16x8, r);
    lacc = MFMA(ones, pb, lacc);         // row-sum of P on the matrix pipe
    #pragma unroll
    for (int dk = 0; dk < 4; ++dk) acc[dk] = MFMA(vf[dk], pb, acc[dk]);
}

template <int KSPLIT>
__global__ __launch_bounds__(256, 3) void attn_fwd(
    const float* __restrict__ Qg, const float* __restrict__ Kg,
    const float* __restrict__ Vg, float* __restrict__ Og,
    float* __restrict__ wsO, float* __restrict__ wsML)
{
    const int h    = blockIdx.y;
    const int qb   = blockIdx.x;
    const int ks   = (KSPLIT > 1) ? blockIdx.z : 0;
    const int NT   = (S_LEN / KVB) / KSPLIT;
    const int tid  = threadIdx.x;
    const int lane = tid & 63;
    const int wv   = tid >> 6;      // wave 0..3, each owns 32 q rows
    const int g    = lane >> 4;     // lane group 0..3
    const int r16  = lane & 15;

    __shared__ __align__(16) unsigned char lds[16384];   // 2 bufs x (K 4K + V 4K)

    // ---- Q fragments: 2 sets of 16 rows, pre-scaled by log2(e)/sqrt(D) ----
    const float QSC = 0.125f * 1.44269504088896f;
    const int qrow0 = qb * QBLK + wv * 32 + r16;
    bf16x8 qf0[2], qf1[2];
    {
        const float* qp0 = Qg + ((size_t)h * S_LEN + qrow0) * DDIM;
        const float* qp1 = qp0 + 16 * DDIM;
        #pragma unroll
        for (int c = 0; c < 2; ++c) {
            float4 x = *reinterpret_cast<const float4*>(qp0 + 32 * c + 8 * g);
            float4 y = *reinterpret_cast<const float4*>(qp0 + 32 * c + 8 * g + 4);
            float4 xs = {x.x * QSC, x.y * QSC, x.z * QSC, x.w * QSC};
            float4 ys = {y.x * QSC, y.y * QSC, y.z * QSC, y.w * QSC};
            qf0[c] = __builtin_bit_cast(bf16x8, cvt8(xs, ys));
            x = *reinterpret_cast<const float4*>(qp1 + 32 * c + 8 * g);
            y = *reinterpret_cast<const float4*>(qp1 + 32 * c + 8 * g + 4);
            xs = {x.x * QSC, x.y * QSC, x.z * QSC, x.w * QSC};
            ys = {y.x * QSC, y.y * QSC, y.z * QSC, y.w * QSC};
            qf1[c] = __builtin_bit_cast(bf16x8, cvt8(xs, ys));
        }
    }

    // ---- identity fragments for the V-transpose MFMA (k-map: 8g+e) ----
    bf16x8 idf[2];
    #pragma unroll
    for (int c2 = 0; c2 < 2; ++c2) {
        #pragma unroll
        for (int e = 0; e < 8; ++e) {
            bool on = ((g >> 1) == c2) && ((r16 >> 3) == (g & 1)) && (e == (r16 & 7));
            idf[c2][e] = on ? (short)0x3F80 : (short)0;
        }
    }
    bf16x8 ones;
    #pragma unroll
    for (int e = 0; e < 8; ++e) ones[e] = (short)0x3F80;

    // ---- staging assignment ----
    const int srow   = tid >> 3;
    const int sd     = (tid & 7) * 8;
    const int swaddr = (srow * 128 + sd * 2) ^ ((srow & 7) << 4);
    const size_t kvoff = (size_t)h * S_LEN * DDIM
                       + (size_t)ks * (S_LEN / KSPLIT) * DDIM
                       + (size_t)srow * DDIM + sd;
    const float* kp = Kg + kvoff;
    const float* vp = Vg + kvoff;

    // prologue: tile 0 -> buf0; tile 1 -> regs
    float4 ka = *reinterpret_cast<const float4*>(kp);
    float4 kb = *reinterpret_cast<const float4*>(kp + 4);
    float4 va = *reinterpret_cast<const float4*>(vp);
    float4 vb = *reinterpret_cast<const float4*>(vp + 4);
    stage(lds, swaddr, ka, kb, va, vb);
    kp += KVB * DDIM; vp += KVB * DDIM;
    ka = *reinterpret_cast<const float4*>(kp);
    kb = *reinterpret_cast<const float4*>(kp + 4);
    va = *reinterpret_cast<const float4*>(vp);
    vb = *reinterpret_cast<const float4*>(vp + 4);
    __syncthreads();

    const f32x4 z0 = {0.f, 0.f, 0.f, 0.f};
    f32x4 accA[4] = {z0, z0, z0, z0};    // set0: d = 16dk+4g+j, q = r16
    f32x4 accB[4] = {z0, z0, z0, z0};    // set1: q = 16 + r16
    f32x4 laccA = z0, laccB = z0;        // running softmax denominators
    float m0 = -INFINITY, m1 = -INFINITY;

    int c = 0;
    for (int kt = 0; kt < NT; ++kt) {
        const unsigned char* Klds = lds + c * 8192;
        const unsigned char* Vlds = lds + c * 8192 + 4096;

        // write next tile into other buffer; issue loads for tile kt+2
        if (kt + 1 < NT) {
            stage(lds + (c ^ 1) * 8192, swaddr, ka, kb, va, vb);
            if (kt + 2 < NT) {
                kp += KVB * DDIM; vp += KVB * DDIM;
                ka = *reinterpret_cast<const float4*>(kp);
                kb = *reinterpret_cast<const float4*>(kp + 4);
                va = *reinterpret_cast<const float4*>(vp);
                vb = *reinterpret_cast<const float4*>(vp + 4);
            }
        }

        // ---- QK^T (swapped): S^T tiles; keys 4g+j (+16), q = r16 ----
        f32x4 sA0 = z0, sA1 = z0, sB0 = z0, sB1 = z0;
        #pragma unroll
        for (int cc = 0; cc < 2; ++cc) {
            bf16x8 k0 = ldfrag(Klds, r16,      32 * cc + 8 * g);
            bf16x8 k1 = ldfrag(Klds, 16 + r16, 32 * cc + 8 * g);
            sA0 = MFMA(k0, qf0[cc], sA0);
            sA1 = MFMA(k1, qf0[cc], sA1);
            sB0 = MFMA(k0, qf1[cc], sB0);
            sB1 = MFMA(k1, qf1[cc], sB1);
        }

        // ---- V^T via identity-MFMA (per-dc to limit live registers) ----
        bf16x8 vf[4];
        #pragma unroll
        for (int dc = 0; dc < 2; ++dc) {
            bf16x8 av0 = ldfrag(Vlds, r16,      32 * dc + 8 * g);
            bf16x8 av1 = ldfrag(Vlds, 16 + r16, 32 * dc + 8 * g);
            #pragma unroll
            for (int ci = 0; ci < 2; ++ci) {
                f32x4 t0 = MFMA(av0, idf[ci], z0);
                f32x4 t1 = MFMA(av1, idf[ci], z0);
                int4 w;
                w.x = (int)pk2t(t0[0], t0[1]); w.y = (int)pk2t(t0[2], t0[3]);
                w.z = (int)pk2t(t1[0], t1[1]); w.w = (int)pk2t(t1[2], t1[3]);
                vf[2 * dc + ci] = __builtin_bit_cast(bf16x8, w);
            }
        }

        sm_pv(sA0, sA1, m0, accA, laccA, vf, ones);
        sm_pv(sB0, sB1, m1, accB, laccB, vf, ones);

        __syncthreads();
        c ^= 1;
    }

    // ---- epilogue (every lane holds the full denominator in lacc[0]) ----
    if (KSPLIT == 1) {
        float inv0 = 1.0f / laccA[0];
        float* op = Og + ((size_t)h * S_LEN + qrow0) * DDIM;
        #pragma unroll
        for (int dk = 0; dk < 4; ++dk) {
            float4 o = {accA[dk][0] * inv0, accA[dk][1] * inv0,
                        accA[dk][2] * inv0, accA[dk][3] * inv0};
            *reinterpret_cast<float4*>(op + 16 * dk + 4 * g) = o;
        }
        float inv1 = 1.0f / laccB[0];
        op += 16 * DDIM;
        #pragma unroll
        for (int dk = 0; dk < 4; ++dk) {
            float4 o = {accB[dk][0] * inv1, accB[dk][1] * inv1,
                        accB[dk][2] * inv1, accB[dk][3] * inv1};
            *reinterpret_cast<float4*>(op + 16 * dk + 4 * g) = o;
        }
    } else {
        // unnormalized partials + (m, l) per row
        const size_t R0 = (size_t)h * S_LEN + qrow0;
        float* o0 = wsO + ((size_t)ks * (NHEAD * S_LEN) + R0) * DDIM;
        #pragma unroll
        for (int dk = 0; dk < 4; ++dk) {
            float4 o = {accA[dk][0], accA[dk][1], accA[dk][2], accA[dk][3]};
            *reinterpret_cast<float4*>(o0 + 16 * dk + 4 * g) = o;
        }
        o0 += 16 * DDIM;
        #pragma unroll
        for (int dk = 0; dk < 4; ++dk) {
            float4 o = {accB[dk][0], accB[dk][1], accB[dk][2], accB[dk][3]};
            *reinterpret_cast<float4*>(o0 + 16 * dk + 4 * g) = o;
        }
        if (g == 0) {
            float2 v0 = {m0, laccA[0]};
            float2 v1 = {m1, laccB[0]};
            *reinterpret_cast<float2*>(wsML + ((size_t)ks * (NHEAD * S_LEN) + R0) * 2)      = v0;
            *reinterpret_cast<float2*>(wsML + ((size_t)ks * (NHEAD * S_LEN) + R0 + 16) * 2) = v1;
        }
    }
}

__global__ __launch_bounds__(256) void combine2(
    const float* __restrict__ wsO, const float* __restrict__ wsML,
    float* __restrict__ Og)
{
    const int NR = NHEAD * S_LEN;
    int t  = blockIdx.x * 256 + threadIdx.x;     // one float4 of O per thread
    int R  = t >> 4;
    int d4 = (t & 15) * 4;
    float2 ml0 = *reinterpret_cast<const float2*>(wsML + (size_t)R * 2);
    float2 ml1 = *reinterpret_cast<const float2*>(wsML + ((size_t)NR + R) * 2);
    float m  = fmaxf(ml0.x, ml1.x);
    float a0 = exp2v(ml0.x - m);
    float a1 = exp2v(ml1.x - m);
    float inv = 1.0f / (a0 * ml0.y + a1 * ml1.y);
    a0 *= inv; a1 *= inv;
    float4 o0 = *reinterpret_cast<const float4*>(wsO + (size_t)R * DDIM + d4);
    float4 o1 = *reinterpret_cast<const float4*>(wsO + ((size_t)NR + R) * DDIM + d4);
    float4 o = {a0 * o0.x + a1 * o1.x, a0 * o0.y + a1 * o1.y,
                a0 * o0.z + a1 * o1.z, a0 * o0.w + a1 * o1.w};
    *reinterpret_cast<float4*>(Og + (size_t)R * DDIM + d4) = o;
}

extern "C" void kernel_launch(void* const* d_in, const int* in_sizes, int n_in,
                              void* d_out, int out_size, void* d_ws, size_t ws_size,
                              hipStream_t stream) {
    const float* Q = (const float*)d_in[0];
    const float* K = (const float*)d_in[1];
    const float* V = (const float*)d_in[2];
    float* O = (float*)d_out;

    const size_t nO  = (size_t)2 * NHEAD * S_LEN * DDIM;   // partial O floats
    const size_t nML = (size_t)2 * NHEAD * S_LEN * 2;      // (m,l) floats
    const size_t need = (nO + nML) * sizeof(float);

    if (ws_size >= need) {
        float* wsO  = (float*)d_ws;
        float* wsML = wsO + nO;
        dim3 grid(S_LEN / QBLK, NHEAD, 2);
        attn_fwd<2><<<grid, dim3(256, 1, 1), 0, stream>>>(Q, K, V, O, wsO, wsML);
        int nthr = NHEAD * S_LEN * (DDIM / 4);
        combine2<<<dim3(nthr / 256), dim3(256, 1, 1), 0, stream>>>(wsO, wsML, O);
    } else {
        dim3 grid(S_LEN / QBLK, NHEAD, 1);
        attn_fwd<1><<<grid, dim3(256, 1, 1), 0, stream>>>(Q, K, V, O, nullptr, nullptr);
    }
}

// Round 9
// 102.684 us; speedup vs baseline: 3.0553x; 1.2104x over previous
//
#include <hip/hip_runtime.h>
#include <hip/hip_bf16.h>

typedef short bf16x8 __attribute__((ext_vector_type(8)));
typedef __bf16 bfv8  __attribute__((ext_vector_type(8)));
typedef __bf16 bfv4  __attribute__((ext_vector_type(4)));
typedef float f32x4  __attribute__((ext_vector_type(4)));

#define S_LEN 4096
#define DDIM  64
#define KVB   32
#define QBLK  128               // q rows per block (4 waves x 32)
#define NHEAD 16
#define THR   7.0f              // defer-max threshold (log2 domain)
#define VOFFB 4096              // V^T region offset inside LDS buffer
#define BUFSZ 9216              // K tile 4096 B + V^T tile 64 rows x 80 B

#define MFMA(a, b, c) __builtin_amdgcn_mfma_f32_16x16x32_bf16((a), (b), (c), 0, 0, 0)

// base-2 exp via v_exp_f32 (avoid __exp2f: glibc macro collision)
static __device__ __forceinline__ float exp2v(float x) {
    return __builtin_amdgcn_exp2f(x);
}

// 8x fp32 -> bf16 RNE via native __bf16 casts (compiler fuses to v_cvt_pk_bf16_f32)
static __device__ __forceinline__ int4 cvt8(float4 a, float4 b) {
    bfv8 r;
    r[0] = (__bf16)a.x; r[1] = (__bf16)a.y; r[2] = (__bf16)a.z; r[3] = (__bf16)a.w;
    r[4] = (__bf16)b.x; r[5] = (__bf16)b.y; r[6] = (__bf16)b.z; r[7] = (__bf16)b.w;
    return __builtin_bit_cast(int4, r);
}
static __device__ __forceinline__ int2 cvt4(f32x4 a) {
    bfv4 r;
    r[0] = (__bf16)a[0]; r[1] = (__bf16)a[1]; r[2] = (__bf16)a[2]; r[3] = (__bf16)a[3];
    return __builtin_bit_cast(int2, r);
}

// K fragment read from row-major [32][64] bf16 LDS tile, XOR-swizzled
static __device__ __forceinline__ bf16x8 ldfrag(const unsigned char* base, int row, int doff) {
    int addr = (row * 128 + doff * 2) ^ ((row & 7) << 4);
    return *reinterpret_cast<const bf16x8*>(base + addr);
}

// stage K (fp32->bf16, swizzled) and V^T (pre-converted bf16, straight copy)
static __device__ __forceinline__ void stage(unsigned char* base, int swK, int swV,
                                             float4 ka, float4 kb, int4 vt) {
    *reinterpret_cast<int4*>(base + swK)         = cvt8(ka, kb);
    *reinterpret_cast<int4*>(base + VOFFB + swV) = vt;
}

// online softmax for one 16-row q-set (base-2 domain) -> bf16 P operand,
// elements INTERLEAVED to match V^T's key layout: pos 2j <- key 4g+j, 2j+1 <- 16+4g+j.
// Common path: NO cross-lane ops (in-lane defer-max; l accumulated by ones-MFMA).
static __device__ __forceinline__ bf16x8 softmax_pb(f32x4 s0, f32x4 s1, float& m,
                                                    f32x4 acc[4], f32x4& lacc) {
    float mx = fmaxf(fmaxf(fmaxf(s0[0], s0[1]), s0[2]),
                     fmaxf(fmaxf(s0[3], s1[0]),
                           fmaxf(s1[1], fmaxf(s1[2], s1[3]))));
    if (!__all(mx <= m + THR)) {        // rare: true max grew past headroom
        float pm = fmaxf(mx, __shfl_xor(mx, 16));
        pm = fmaxf(pm, __shfl_xor(pm, 32));
        float mn = fmaxf(m, pm);
        float al = exp2v(m - mn);
        #pragma unroll
        for (int dk = 0; dk < 4; ++dk)
            #pragma unroll
            for (int j = 0; j < 4; ++j) acc[dk][j] *= al;
        #pragma unroll
        for (int j = 0; j < 4; ++j) lacc[j] *= al;
        m = mn;
    }
    bfv8 r;
    #pragma unroll
    for (int j = 0; j < 4; ++j) {
        r[2 * j]     = (__bf16)exp2v(s0[j] - m);
        r[2 * j + 1] = (__bf16)exp2v(s1[j] - m);
    }
    return __builtin_bit_cast(bf16x8, r);
}

// ---- pre-kernel: V [h][key][d] fp32 -> V^T bf16 [h][d][kt][32 interleaved keys] ----
__global__ __launch_bounds__(256) void transpose_v(
    const float* __restrict__ Vg, unsigned short* __restrict__ wsVT)
{
    const int h  = blockIdx.y;
    const int kt = blockIdx.x;                 // 0..127
    const int t  = threadIdx.x;
    __shared__ __align__(16) unsigned short vt[32][68];   // [key][d], padded stride

    {
        const int key = t >> 3;
        const int d0  = (t & 7) * 8;
        const float* vp = Vg + (((size_t)h * S_LEN) + (size_t)kt * 32 + key) * DDIM + d0;
        float4 a = *reinterpret_cast<const float4*>(vp);
        float4 b = *reinterpret_cast<const float4*>(vp + 4);
        int4 w = cvt8(a, b);
        int2 lo = {w.x, w.y}, hi = {w.z, w.w};
        *reinterpret_cast<int2*>(&vt[key][d0])     = lo;   // 8B writes (68-stride => 8B align)
        *reinterpret_cast<int2*>(&vt[key][d0 + 4]) = hi;
    }
    __syncthreads();
    {
        const int d  = t >> 2;
        const int p0 = (t & 3) * 8;
        unsigned short out[8];
        #pragma unroll
        for (int i = 0; i < 8; ++i) {
            int p   = p0 + i;
            int key = 4 * (p >> 3) + ((p & 7) >> 1) + 16 * (p & 1);   // interleave map
            out[i] = vt[key][d];
        }
        size_t off = (((size_t)h * DDIM + d) * 128 + kt) * 32 + p0;
        *reinterpret_cast<int4*>(wsVT + off) = *reinterpret_cast<const int4*>(out);
    }
}

template <int KSPLIT>
__global__ __launch_bounds__(256, 3) void attn_fwd(
    const float* __restrict__ Qg, const float* __restrict__ Kg,
    const unsigned short* __restrict__ wsVT, float* __restrict__ Og,
    unsigned short* __restrict__ wsO, float* __restrict__ wsML)
{
    const int h    = blockIdx.y;
    const int qb   = blockIdx.x;
    const int ks   = (KSPLIT > 1) ? blockIdx.z : 0;
    const int NT   = (S_LEN / KVB) / KSPLIT;
    const int tid  = threadIdx.x;
    const int lane = tid & 63;
    const int wv   = tid >> 6;      // wave 0..3, each owns 32 q rows
    const int g    = lane >> 4;     // lane group 0..3
    const int r16  = lane & 15;

    __shared__ __align__(16) unsigned char lds[2 * BUFSZ];

    // ---- Q fragments: 2 sets of 16 rows, pre-scaled by log2(e)/sqrt(D) ----
    const float QSC = 0.125f * 1.44269504088896f;
    const int qrow0 = qb * QBLK + wv * 32 + r16;
    bf16x8 qf0[2], qf1[2];
    {
        const float* qp0 = Qg + ((size_t)h * S_LEN + qrow0) * DDIM;
        const float* qp1 = qp0 + 16 * DDIM;
        #pragma unroll
        for (int c = 0; c < 2; ++c) {
            float4 x = *reinterpret_cast<const float4*>(qp0 + 32 * c + 8 * g);
            float4 y = *reinterpret_cast<const float4*>(qp0 + 32 * c + 8 * g + 4);
            float4 xs = {x.x * QSC, x.y * QSC, x.z * QSC, x.w * QSC};
            float4 ys = {y.x * QSC, y.y * QSC, y.z * QSC, y.w * QSC};
            qf0[c] = __builtin_bit_cast(bf16x8, cvt8(xs, ys));
            x = *reinterpret_cast<const float4*>(qp1 + 32 * c + 8 * g);
            y = *reinterpret_cast<const float4*>(qp1 + 32 * c + 8 * g + 4);
            xs = {x.x * QSC, x.y * QSC, x.z * QSC, x.w * QSC};
            ys = {y.x * QSC, y.y * QSC, y.z * QSC, y.w * QSC};
            qf1[c] = __builtin_bit_cast(bf16x8, cvt8(xs, ys));
        }
    }

    bf16x8 ones;
    #pragma unroll
    for (int e = 0; e < 8; ++e) ones[e] = (short)0x3F80;

    // ---- staging assignment ----
    // K: swizzled row-major [32][64] (fp32 source, cvt on the fly).
    // V^T: [64 d][32 k-interleaved] bf16, rows padded to 80 B (straight copy from wsVT).
    const int srow = tid >> 3;                 // K: key row 0..31
    const int sd   = (tid & 7) * 8;            // K: d offset
    const int swK  = (srow * 128 + sd * 2) ^ ((srow & 7) << 4);
    const int vrow = tid >> 2;                 // V^T: d row 0..63
    const int swV  = vrow * 80 + (tid & 3) * 16;

    const float* kp = Kg + (size_t)h * S_LEN * DDIM
                    + (size_t)ks * (S_LEN / KSPLIT) * DDIM
                    + (size_t)srow * DDIM + sd;
    const unsigned short* vtp = wsVT
        + (((size_t)h * DDIM + vrow) * 128 + (size_t)ks * (128 / KSPLIT)) * 32
        + (tid & 3) * 8;

    // prologue: tile 0 -> buf0; tile 1 -> regs
    float4 ka = *reinterpret_cast<const float4*>(kp);
    float4 kb = *reinterpret_cast<const float4*>(kp + 4);
    int4   vt = *reinterpret_cast<const int4*>(vtp);
    stage(lds, swK, swV, ka, kb, vt);
    kp += KVB * DDIM; vtp += 32;
    ka = *reinterpret_cast<const float4*>(kp);
    kb = *reinterpret_cast<const float4*>(kp + 4);
    vt = *reinterpret_cast<const int4*>(vtp);
    __syncthreads();

    const f32x4 z0 = {0.f, 0.f, 0.f, 0.f};
    f32x4 accA[4] = {z0, z0, z0, z0};    // set0: d = 16dk+4g+j, q = r16
    f32x4 accB[4] = {z0, z0, z0, z0};    // set1: q = 16 + r16
    f32x4 laccA = z0, laccB = z0;        // running softmax denominators
    float m0 = -INFINITY, m1 = -INFINITY;

    int c = 0;
    for (int kt = 0; kt < NT; ++kt) {
        const unsigned char* Klds = lds + c * BUFSZ;
        const unsigned char* Vlds = Klds + VOFFB;

        // write next tile into other buffer; issue loads for tile kt+2
        if (kt + 1 < NT) {
            stage(lds + (c ^ 1) * BUFSZ, swK, swV, ka, kb, vt);
            if (kt + 2 < NT) {
                kp += KVB * DDIM; vtp += 32;
                ka = *reinterpret_cast<const float4*>(kp);
                kb = *reinterpret_cast<const float4*>(kp + 4);
                vt = *reinterpret_cast<const int4*>(vtp);
            }
        }

        // ---- V^T fragments: one b128 each, issued early (independent of scores) ----
        bf16x8 vf[4];
        {
            const unsigned char* vbase = Vlds + r16 * 80 + 16 * g;
            #pragma unroll
            for (int dk = 0; dk < 4; ++dk)
                vf[dk] = *reinterpret_cast<const bf16x8*>(vbase + dk * 1280);
        }

        // ---- QK^T (swapped): S^T tiles; keys 4g+j (+16), q = r16 ----
        f32x4 sA0 = z0, sA1 = z0, sB0 = z0, sB1 = z0;
        #pragma unroll
        for (int cc = 0; cc < 2; ++cc) {
            bf16x8 k0 = ldfrag(Klds, r16,      32 * cc + 8 * g);
            bf16x8 k1 = ldfrag(Klds, 16 + r16, 32 * cc + 8 * g);
            sA0 = MFMA(k0, qf0[cc], sA0);
            sA1 = MFMA(k1, qf0[cc], sA1);
            sB0 = MFMA(k0, qf1[cc], sB0);
            sB1 = MFMA(k1, qf1[cc], sB1);
        }

        // ---- softmax (interleaved P to match V^T key order) ----
        bf16x8 pbA = softmax_pb(sA0, sA1, m0, accA, laccA);
        bf16x8 pbB = softmax_pb(sB0, sB1, m1, accB, laccB);

        // ---- PV + denominator on the matrix pipe ----
        laccA = MFMA(ones, pbA, laccA);
        #pragma unroll
        for (int dk = 0; dk < 4; ++dk) accA[dk] = MFMA(vf[dk], pbA, accA[dk]);
        laccB = MFMA(ones, pbB, laccB);
        #pragma unroll
        for (int dk = 0; dk < 4; ++dk) accB[dk] = MFMA(vf[dk], pbB, accB[dk]);

        __syncthreads();
        c ^= 1;
    }

    // ---- epilogue (every lane holds the full denominator in lacc[0]) ----
    if (KSPLIT == 1) {
        float inv0 = 1.0f / laccA[0];
        float* op = Og + ((size_t)h * S_LEN + qrow0) * DDIM;
        #pragma unroll
        for (int dk = 0; dk < 4; ++dk) {
            float4 o = {accA[dk][0] * inv0, accA[dk][1] * inv0,
                        accA[dk][2] * inv0, accA[dk][3] * inv0};
            *reinterpret_cast<float4*>(op + 16 * dk + 4 * g) = o;
        }
        float inv1 = 1.0f / laccB[0];
        op += 16 * DDIM;
        #pragma unroll
        for (int dk = 0; dk < 4; ++dk) {
            float4 o = {accB[dk][0] * inv1, accB[dk][1] * inv1,
                        accB[dk][2] * inv1, accB[dk][3] * inv1};
            *reinterpret_cast<float4*>(op + 16 * dk + 4 * g) = o;
        }
    } else {
        // unnormalized bf16 partials + (m, l) per row
        const size_t R0 = (size_t)h * S_LEN + qrow0;
        unsigned short* o0 = wsO + ((size_t)ks * (NHEAD * S_LEN) + R0) * DDIM;
        #pragma unroll
        for (int dk = 0; dk < 4; ++dk)
            *reinterpret_cast<int2*>(o0 + 16 * dk + 4 * g) = cvt4(accA[dk]);
        o0 += 16 * DDIM;
        #pragma unroll
        for (int dk = 0; dk < 4; ++dk)
            *reinterpret_cast<int2*>(o0 + 16 * dk + 4 * g) = cvt4(accB[dk]);
        if (g == 0) {
            float2 v0 = {m0, laccA[0]};
            float2 v1 = {m1, laccB[0]};
            *reinterpret_cast<float2*>(wsML + ((size_t)ks * (NHEAD * S_LEN) + R0) * 2)      = v0;
            *reinterpret_cast<float2*>(wsML + ((size_t)ks * (NHEAD * S_LEN) + R0 + 16) * 2) = v1;
        }
    }
}

__global__ __launch_bounds__(256) void combine2(
    const unsigned short* __restrict__ wsO, const float* __restrict__ wsML,
    float* __restrict__ Og)
{
    const int NR = NHEAD * S_LEN;
    int t  = blockIdx.x * 256 + threadIdx.x;     // one float4 of O per thread
    int R  = t >> 4;
    int d4 = (t & 15) * 4;
    float2 ml0 = *reinterpret_cast<const float2*>(wsML + (size_t)R * 2);
    float2 ml1 = *reinterpret_cast<const float2*>(wsML + ((size_t)NR + R) * 2);
    float m  = fmaxf(ml0.x, ml1.x);
    float a0 = exp2v(ml0.x - m);
    float a1 = exp2v(ml1.x - m);
    float inv = 1.0f / (a0 * ml0.y + a1 * ml1.y);
    a0 *= inv; a1 *= inv;
    bfv4 o0 = __builtin_bit_cast(bfv4,
        *reinterpret_cast<const int2*>(wsO + (size_t)R * DDIM + d4));
    bfv4 o1 = __builtin_bit_cast(bfv4,
        *reinterpret_cast<const int2*>(wsO + ((size_t)NR + R) * DDIM + d4));
    float4 o = {a0 * (float)o0[0] + a1 * (float)o1[0],
                a0 * (float)o0[1] + a1 * (float)o1[1],
                a0 * (float)o0[2] + a1 * (float)o1[2],
                a0 * (float)o0[3] + a1 * (float)o1[3]};
    *reinterpret_cast<float4*>(Og + (size_t)R * DDIM + d4) = o;
}

extern "C" void kernel_launch(void* const* d_in, const int* in_sizes, int n_in,
                              void* d_out, int out_size, void* d_ws, size_t ws_size,
                              hipStream_t stream) {
    const float* Q = (const float*)d_in[0];
    const float* K = (const float*)d_in[1];
    const float* V = (const float*)d_in[2];
    float* O = (float*)d_out;

    const size_t nVT = (size_t)NHEAD * DDIM * S_LEN;        // V^T bf16 elems
    const size_t nO  = (size_t)2 * NHEAD * S_LEN * DDIM;    // partial O bf16 elems
    const size_t nML = (size_t)2 * NHEAD * S_LEN * 2;       // (m,l) floats
    const size_t needVT   = nVT * 2;
    const size_t needFull = nVT * 2 + nO * 2 + nML * 4;     // ~26.2 MB

    unsigned short* wsVT = (unsigned short*)d_ws;
    transpose_v<<<dim3(128, NHEAD), dim3(256, 1, 1), 0, stream>>>(V, wsVT);

    if (ws_size >= needFull) {
        unsigned short* wsO  = wsVT + nVT;
        float*          wsML = (float*)(wsO + nO);
        dim3 grid(S_LEN / QBLK, NHEAD, 2);
        attn_fwd<2><<<grid, dim3(256, 1, 1), 0, stream>>>(Q, K, wsVT, O, wsO, wsML);
        int nthr = NHEAD * S_LEN * (DDIM / 4);
        combine2<<<dim3(nthr / 256), dim3(256, 1, 1), 0, stream>>>(wsO, wsML, O);
    } else if (ws_size >= needVT) {
        dim3 grid(S_LEN / QBLK, NHEAD, 1);
        attn_fwd<1><<<grid, dim3(256, 1, 1), 0, stream>>>(Q, K, wsVT, O, nullptr, nullptr);
    }
}